// Round 3
// baseline (841.751 us; speedup 1.0000x reference)
//
#include <hip/hip_runtime.h>

// ROI Align (FPN multi-level), OUT=7, ratio=2. Block-per-ROI, LDS-staged.
// FPN invariant: footprint area at assigned level is bounded (span_x*span_y =
// area*scale^2 <= ~28^2), identical for all 256 channels. Stage footprint for
// G=8 channels at a time into LDS with coalesced row loads (lanes sweep x),
// then compute 49 bins/channel from LDS. Axis weights computed once per ROI.
// Round-1 lesson: per-thread scattered gathers cost ~40 cache lines per
// wave-gather (TA-bound, 203us). Round-2 lesson: per-thread ILP doesn't
// materialize at 36 VGPRs; keep TLP high, fix address locality instead.

#define NCH 256
#define POOL 7
#define NBIN 49          // 7*7
#define G 8              // channels per LDS pass
#define CAP 1160         // floats per channel region (max FH*RS ~ 1020 + margin)
#define NSAMP 14         // OUT * RATIO

__global__ __launch_bounds__(256) void roi_align_kernel(
    const float* __restrict__ f0, const float* __restrict__ f1,
    const float* __restrict__ f2, const float* __restrict__ f3,
    const float* __restrict__ boxes, const int* __restrict__ bidx,
    float* __restrict__ out, int M)
{
    __shared__ float sF[G * CAP];
    __shared__ int   sxlo[NSAMP], sxhi[NSAMP], sylo[NSAMP], syhi[NSAMP];
    __shared__ float swxl[NSAMP], swxh[NSAMP], swyl[NSAMP], swyh[NSAMP];

    const int m   = blockIdx.x;
    const int tid = threadIdx.x;
    if (m >= M) return;

    // ---- box + level (uniform across block; cheap, every thread) ----
    float bx0 = boxes[4 * m + 0];
    float by0 = boxes[4 * m + 1];
    float bx1 = boxes[4 * m + 2];
    float by1 = boxes[4 * m + 3];

    float area = (bx1 - bx0) * (by1 - by0);
    float sz   = sqrtf(area);
    float lvlf = floorf(4.0f + log2f(sz / 224.0f + 1e-8f));
    lvlf = fminf(fmaxf(lvlf, 2.0f), 5.0f);
    int lvl = (int)lvlf - 2;

    const float* fp; int H; int W; float scale;
    if (lvl == 0)      { fp = f0; H = 200; W = 304; scale = 0.25f;    }
    else if (lvl == 1) { fp = f1; H = 100; W = 152; scale = 0.125f;   }
    else if (lvl == 2) { fp = f2; H = 50;  W = 76;  scale = 0.0625f;  }
    else               { fp = f3; H = 25;  W = 38;  scale = 0.03125f; }

    float x0 = bx0 * scale - 0.5f;
    float y0 = by0 * scale - 0.5f;
    float bin_w = (bx1 * scale - 0.5f - x0) * (1.0f / 7.0f);
    float bin_h = (by1 * scale - 0.5f - y0) * (1.0f / 7.0f);

    // ---- per-ROI axis weights (28 threads), matches _axis_weights ----
    if (tid < 2 * NSAMP) {
        int axis = tid / NSAMP;          // 0 = x, 1 = y
        int s    = tid % NSAMP;
        float off = (float)(s >> 1) + ((s & 1) ? 0.75f : 0.25f);
        float c    = axis ? (y0 + bin_h * off) : (x0 + bin_w * off);
        float size = axis ? (float)H : (float)W;
        float valid = (c >= -1.0f && c <= size) ? 1.0f : 0.0f;
        float cc    = fmaxf(c, 0.0f);
        float lo_f  = floorf(cc);
        bool  cap   = lo_f >= size - 1.0f;
        int   lo    = cap ? (int)size - 1 : (int)lo_f;
        int   hi    = cap ? lo : lo + 1;
        float l     = cap ? 0.0f : (cc - lo_f);
        float wlo   = (1.0f - l) * valid;
        float whi   = l * valid;
        if (axis) { sylo[s] = lo; syhi[s] = hi; swyl[s] = wlo; swyh[s] = whi; }
        else      { sxlo[s] = lo; sxhi[s] = hi; swxl[s] = wlo; swxh[s] = whi; }
    }
    __syncthreads();

    // ---- footprint rect (indices are monotone in s) ----
    const int rx0 = sxlo[0];
    const int ry0 = sylo[0];
    const int FW  = sxhi[NSAMP - 1] - rx0 + 1;   // <= ~105
    int       FH  = syhi[NSAMP - 1] - ry0 + 1;
    const int RS  = FW + 1;                       // +1 pad col (zeroed)
    if (FH * RS > CAP) FH = CAP / RS;             // impossible-case guard

    const size_t HW = (size_t)(H * W);
    const float* fbase = fp + (size_t)bidx[m] * NCH * HW
                            + (size_t)ry0 * W + rx0;

    const int fyg = tid >> 5;    // row group 0..7
    const int fxl = tid & 31;    // lane within row

    for (int chunk = 0; chunk < NCH / G; ++chunk) {
        const float* csrc = fbase + (size_t)(chunk * G) * HW;

        // ---- stage G channels' footprints, coalesced along x ----
        for (int fy = fyg; fy < FH; fy += 8) {
            for (int fx = fxl; fx < RS; fx += 32) {
                bool real = fx < FW;
                const float* sp = csrc + (size_t)fy * W + fx;
                int dofs = fy * RS + fx;
                #pragma unroll
                for (int c_l = 0; c_l < G; ++c_l) {
                    // unrolled: 8 independent loads in flight per iteration
                    sF[c_l * CAP + dofs] = real ? sp[c_l * HW] : 0.0f;
                }
            }
        }
        __syncthreads();

        // ---- compute: t -> (c_l, bin); out offsets == t (coalesced) ----
        for (int t = tid; t < G * NBIN; t += 256) {
            int c_l = t / NBIN;
            int bin = t - c_l * NBIN;
            int py  = bin / POOL;
            int px  = bin - py * POOL;
            const float* F = &sF[c_l * CAP];
            float acc = 0.0f;
            #pragma unroll
            for (int sy = 0; sy < 2; ++sy) {
                int   ysi = 2 * py + sy;
                int   yl  = sylo[ysi] - ry0;
                int   yh  = syhi[ysi] - ry0;
                float wl  = swyl[ysi];
                float wh  = swyh[ysi];
                const float* rl = F + yl * RS;
                const float* rh = F + yh * RS;
                #pragma unroll
                for (int sx = 0; sx < 2; ++sx) {
                    int   xsi = 2 * px + sx;
                    int   xr  = sxlo[xsi] - rx0;
                    float wxl = swxl[xsi];
                    float wxh = swxh[xsi];
                    // capped-x: wxh==0 and [xr+1] hits the zeroed pad col
                    acc += wl * (rl[xr] * wxl + rl[xr + 1] * wxh)
                         + wh * (rh[xr] * wxl + rh[xr + 1] * wxh);
                }
            }
            out[((size_t)m * NCH + chunk * G) * NBIN + t] = acc * 0.25f;
        }
        __syncthreads();
    }
}

extern "C" void kernel_launch(void* const* d_in, const int* in_sizes, int n_in,
                              void* d_out, int out_size, void* d_ws, size_t ws_size,
                              hipStream_t stream) {
    const float* f0    = (const float*)d_in[0];
    const float* f1    = (const float*)d_in[1];
    const float* f2    = (const float*)d_in[2];
    const float* f3    = (const float*)d_in[3];
    const float* boxes = (const float*)d_in[4];
    const int*   bidx  = (const int*)d_in[5];
    float* out = (float*)d_out;

    int M = in_sizes[4] / 4;
    hipLaunchKernelGGL(roi_align_kernel, dim3(M), dim3(256), 0, stream,
                       f0, f1, f2, f3, boxes, bidx, out, M);
}

// Round 4
// 361.427 us; speedup vs baseline: 2.3290x; 2.3290x over previous
//
#include <hip/hip_runtime.h>

// ROI Align (FPN multi-level), OUT=7, ratio=2.
// WAVE-per-(ROI,channel): each 64-lane wave independently stages one
// channel's footprint into its private LDS slice (coalesced row loads,
// depth-2 pipelined), then computes its 49 bins from LDS. ZERO barriers.
// Round-1 lesson: per-thread gathers = ~40 cache lines per wave-gather ->
//   TA-bound at 203us (125M line transactions). Staging rows coalesced cuts
//   line transactions ~12x.
// Round-3 lesson: block-level staging + 64 syncthreads + 1000-block grid
//   collapses occupancy (16%). This design: 64000 blocks, 32 waves/CU
//   (20.2KB LDS/block -> 8 blocks/CU), no cross-wave coupling.
// FPN bound: footprint area <= ~(26+3)x(26+2) ~ 982 floats (span_gm < 28,
//   per-axis <= ~103 for thin boxes). CAP=1152 covers worst case.

#define NCH 256
#define POOL 7
#define NBIN 49
#define NSAMP 14
#define CAP 1152
#define WPB 4            // waves per 256-thread block

__global__ __launch_bounds__(256, 8) void roi_align_kernel(
    const float* __restrict__ f0, const float* __restrict__ f1,
    const float* __restrict__ f2, const float* __restrict__ f3,
    const float* __restrict__ boxes, const int* __restrict__ bidx,
    float* __restrict__ out, int M)
{
    __shared__ float sF[WPB][CAP];
    __shared__ int   sXlo[WPB][NSAMP], sXhi[WPB][NSAMP];
    __shared__ int   sYlo[WPB][NSAMP], sYhi[WPB][NSAMP];
    __shared__ float sWxl[WPB][NSAMP], sWxh[WPB][NSAMP];
    __shared__ float sWyl[WPB][NSAMP], sWyh[WPB][NSAMP];

    const int lane = threadIdx.x & 63;
    const int w    = __builtin_amdgcn_readfirstlane(threadIdx.x >> 6);
    const int unit = blockIdx.x * WPB + w;           // (m, c) pair, scalar
    if (unit >= M * NCH) return;
    const int m = unit >> 8;
    const int c = unit & (NCH - 1);

    // ---- box + level (wave-uniform; scalarized by compiler) ----
    float bx0 = boxes[4 * m + 0];
    float by0 = boxes[4 * m + 1];
    float bx1 = boxes[4 * m + 2];
    float by1 = boxes[4 * m + 3];

    float area = (bx1 - bx0) * (by1 - by0);
    float sz   = sqrtf(area);
    float lvlf = floorf(4.0f + log2f(sz / 224.0f + 1e-8f));
    lvlf = fminf(fmaxf(lvlf, 2.0f), 5.0f);
    int lvl = (int)lvlf - 2;

    const float* fp; int H; int W; float scale;
    if (lvl == 0)      { fp = f0; H = 200; W = 304; scale = 0.25f;    }
    else if (lvl == 1) { fp = f1; H = 100; W = 152; scale = 0.125f;   }
    else if (lvl == 2) { fp = f2; H = 50;  W = 76;  scale = 0.0625f;  }
    else               { fp = f3; H = 25;  W = 38;  scale = 0.03125f; }

    float x0 = bx0 * scale - 0.5f;
    float y0 = by0 * scale - 0.5f;
    float bin_w = (bx1 * scale - 0.5f - x0) * (1.0f / 7.0f);
    float bin_h = (by1 * scale - 0.5f - y0) * (1.0f / 7.0f);

    // ---- axis weights: 28 lanes in parallel (matches _axis_weights) ----
    if (lane < 2 * NSAMP) {
        int axis = lane >= NSAMP;        // 0 = x, 1 = y
        int s    = axis ? (lane - NSAMP) : lane;
        float off = (float)(s >> 1) + ((s & 1) ? 0.75f : 0.25f);
        float cv    = axis ? (y0 + bin_h * off) : (x0 + bin_w * off);
        float size  = axis ? (float)H : (float)W;
        float valid = (cv >= -1.0f && cv <= size) ? 1.0f : 0.0f;
        float cc    = fmaxf(cv, 0.0f);
        float lo_f  = floorf(cc);
        bool  cap   = lo_f >= size - 1.0f;
        int   lo    = cap ? (int)size - 1 : (int)lo_f;
        int   hi    = cap ? lo : lo + 1;
        float l     = cap ? 0.0f : (cc - lo_f);
        float wlo   = (1.0f - l) * valid;
        float whi   = l * valid;
        if (axis) { sYlo[w][s] = lo; sYhi[w][s] = hi;
                    sWyl[w][s] = wlo; sWyh[w][s] = whi; }
        else      { sXlo[w][s] = lo; sXhi[w][s] = hi;
                    sWxl[w][s] = wlo; sWxh[w][s] = whi; }
    }
    // intra-wave: compiler inserts lgkmcnt wait before aliasing ds_reads

    const int rx0 = sXlo[w][0];
    const int ry0 = sYlo[w][0];
    const int FW  = sXhi[w][NSAMP - 1] - rx0 + 1;
    int       FH  = sYhi[w][NSAMP - 1] - ry0 + 1;
    const int RS  = FW + 1;                 // +1 zeroed pad col (cap-x case)
    if (FH * RS > CAP) FH = CAP / RS;       // unreachable safety guard

    const size_t HW = (size_t)(H * W);
    const float* src = fp + ((size_t)bidx[m] * NCH + c) * HW
                          + (size_t)ry0 * W + rx0;

    // ---- stage footprint: rows coalesced, depth-2 pipelined ----
    if (RS <= 64) {
        int rpi = 64 / RS;                  // rows per wave iteration
        int sfy = lane / RS;
        int sfx = lane - sfy * RS;
        if (sfy < rpi) {
            bool real = sfx < FW;
            int fy = sfy;
            float v = (real && fy < FH) ? src[(size_t)fy * W + sfx] : 0.0f;
            while (fy < FH) {
                int fy2 = fy + rpi;
                float v2 = (real && fy2 < FH) ? src[(size_t)fy2 * W + sfx] : 0.0f;
                sF[w][fy * RS + sfx] = v;
                v = v2;
                fy = fy2;
            }
        }
    } else {                                 // very wide-thin ROIs (rare)
        for (int fy = 0; fy < FH; ++fy)
            for (int fx = lane; fx < RS; fx += 64)
                sF[w][fy * RS + fx] = (fx < FW) ? src[(size_t)fy * W + fx] : 0.0f;
    }

    // ---- compute 49 bins from LDS (lanes 0..48) ----
    if (lane < NBIN) {
        int py = lane / POOL;
        int px = lane - POOL * py;
        float acc = 0.0f;
        #pragma unroll
        for (int sy = 0; sy < 2; ++sy) {
            int   ysi = 2 * py + sy;
            int   yl  = sYlo[w][ysi] - ry0;
            int   yh  = sYhi[w][ysi] - ry0;
            float wl  = sWyl[w][ysi];
            float wh  = sWyh[w][ysi];
            const float* rl = &sF[w][yl * RS];
            const float* rh = &sF[w][yh * RS];
            #pragma unroll
            for (int sx = 0; sx < 2; ++sx) {
                int   xsi = 2 * px + sx;
                int   xr  = sXlo[w][xsi] - rx0;
                float wxl = sWxl[w][xsi];
                float wxh = sWxh[w][xsi];
                // cap-x: wxh==0 and [xr+1] hits the zeroed pad column
                acc += wl * (rl[xr] * wxl + rl[xr + 1] * wxh)
                     + wh * (rh[xr] * wxl + rh[xr + 1] * wxh);
            }
        }
        out[(size_t)unit * NBIN + lane] = acc * 0.25f;
    }
}

extern "C" void kernel_launch(void* const* d_in, const int* in_sizes, int n_in,
                              void* d_out, int out_size, void* d_ws, size_t ws_size,
                              hipStream_t stream) {
    const float* f0    = (const float*)d_in[0];
    const float* f1    = (const float*)d_in[1];
    const float* f2    = (const float*)d_in[2];
    const float* f3    = (const float*)d_in[3];
    const float* boxes = (const float*)d_in[4];
    const int*   bidx  = (const int*)d_in[5];
    float* out = (float*)d_out;

    int M = in_sizes[4] / 4;
    int units = M * NCH;
    int blocks = (units + WPB - 1) / WPB;
    hipLaunchKernelGGL(roi_align_kernel, dim3(blocks), dim3(256), 0, stream,
                       f0, f1, f2, f3, boxes, bidx, out, M);
}

// Round 5
// 295.212 us; speedup vs baseline: 2.8513x; 1.2243x over previous
//
#include <hip/hip_runtime.h>

// ROI Align (FPN multi-level), OUT=7, ratio=2. Wave-per-(ROI,channel).
// Round-4 post-mortem: 690 VALU instr/wave (68% VALUBusy) + only 2
// outstanding loads/wave. Fix: async global_load_lds (width 16) staging —
// 1 instr + 2 adds per 1KB chunk, ALL chunks in flight before one waitcnt —
// and a leaner compute phase (no pad column; clamp xr+1, weight is 0 there).
// Zero barriers; 20.2 KB LDS/block -> 8 blocks/CU -> 32 waves/CU.

#define NCH 256
#define POOL 7
#define NBIN 49
#define NSAMP 14
#define CAP 1152          // floats per wave footprint region (max ~1040)
#define WPB 4             // waves per 256-thread block

typedef __attribute__((address_space(3))) void       as3_void;
typedef __attribute__((address_space(1))) const void as1_void;

__global__ __launch_bounds__(256, 8) void roi_align_kernel(
    const float* __restrict__ f0, const float* __restrict__ f1,
    const float* __restrict__ f2, const float* __restrict__ f3,
    const float* __restrict__ boxes, const int* __restrict__ bidx,
    float* __restrict__ out, int M)
{
    __shared__ float sF[WPB][CAP];
    __shared__ int   sXlo[WPB][NSAMP], sXhi[WPB][NSAMP];
    __shared__ int   sYlo[WPB][NSAMP], sYhi[WPB][NSAMP];
    __shared__ float sWxl[WPB][NSAMP], sWxh[WPB][NSAMP];
    __shared__ float sWyl[WPB][NSAMP], sWyh[WPB][NSAMP];

    const int lane = threadIdx.x & 63;
    const int w    = __builtin_amdgcn_readfirstlane(threadIdx.x >> 6);
    const int unit = blockIdx.x * WPB + w;            // (m, c), wave-uniform
    if (unit >= M * NCH) return;
    const int m = unit >> 8;
    const int c = unit & (NCH - 1);

    // ---- box + level (uniform; boxes/bidx loads scalarize) ----
    float bx0 = boxes[4 * m + 0];
    float by0 = boxes[4 * m + 1];
    float bx1 = boxes[4 * m + 2];
    float by1 = boxes[4 * m + 3];

    float area = (bx1 - bx0) * (by1 - by0);
    float sz   = sqrtf(area);
    float lvlf = floorf(4.0f + log2f(sz / 224.0f + 1e-8f));
    lvlf = fminf(fmaxf(lvlf, 2.0f), 5.0f);
    int lvl = (int)lvlf - 2;

    const float* fp; int H; int W; float scale;
    if (lvl == 0)      { fp = f0; H = 200; W = 304; scale = 0.25f;    }
    else if (lvl == 1) { fp = f1; H = 100; W = 152; scale = 0.125f;   }
    else if (lvl == 2) { fp = f2; H = 50;  W = 76;  scale = 0.0625f;  }
    else               { fp = f3; H = 25;  W = 38;  scale = 0.03125f; }

    float x0 = bx0 * scale - 0.5f;
    float y0 = by0 * scale - 0.5f;
    float bin_w = (bx1 * scale - 0.5f - x0) * (1.0f / 7.0f);
    float bin_h = (by1 * scale - 0.5f - y0) * (1.0f / 7.0f);

    // ---- axis weights: 28 lanes in parallel (matches _axis_weights) ----
    if (lane < 2 * NSAMP) {
        int axis = lane >= NSAMP;
        int s    = axis ? (lane - NSAMP) : lane;
        float off = (float)(s >> 1) + ((s & 1) ? 0.75f : 0.25f);
        float cv    = axis ? (y0 + bin_h * off) : (x0 + bin_w * off);
        float size  = axis ? (float)H : (float)W;
        float valid = (cv >= -1.0f && cv <= size) ? 1.0f : 0.0f;
        float cc    = fmaxf(cv, 0.0f);
        float lo_f  = floorf(cc);
        bool  cap   = lo_f >= size - 1.0f;
        int   lo    = cap ? (int)size - 1 : (int)lo_f;
        int   hi    = cap ? lo : lo + 1;
        float l     = cap ? 0.0f : (cc - lo_f);
        float wlo   = (1.0f - l) * valid;
        float whi   = l * valid;
        if (axis) { sYlo[w][s] = lo; sYhi[w][s] = hi;
                    sWyl[w][s] = wlo; sWyh[w][s] = whi; }
        else      { sXlo[w][s] = lo; sXhi[w][s] = hi;
                    sWxl[w][s] = wlo; sWxh[w][s] = whi; }
    }
    // intra-wave ds dependencies: compiler inserts lgkm waits

    // ---- footprint rect from tables (consistent by construction) ----
    const int rx0 = sXlo[w][0];
    const int ry0 = sYlo[w][0];
    const int FW  = sXhi[w][NSAMP - 1] - rx0 + 1;   // <= ~104
    const int FH  = sYhi[w][NSAMP - 1] - ry0 + 1;   // <= ~100
    const int lpr = (FW + 3) >> 2;                  // 16B lanes per row
    const int RS4 = lpr << 2;                       // LDS row pitch (floats)

    const size_t HW = (size_t)(H * W);
    const float* src  = fp + ((size_t)bidx[m] * NCH + c) * HW
                           + (size_t)ry0 * W + rx0;
    const float* fend = fp + (size_t)2 * NCH * HW;

    // async path is safe unless the padded last-row window passes buffer end
    bool safe16 = (src + (size_t)(FH - 1) * W + RS4 <= fend)
               && (FH * RS4 <= CAP);

    if (safe16) {
        int rpi   = 64 / lpr;                       // rows per iteration >=2
        int iters = (FH + rpi - 1) / rpi;           // <= ~6
        int sfy   = lane / lpr;
        int sfx4  = (lane - sfy * lpr) << 2;
        if (sfy < rpi) {
            const float* g    = src + (size_t)sfy * W + sfx4;
            const float* gmax = src + (size_t)(FH - 1) * W + sfx4;
            const size_t gstep = (size_t)rpi * W;
            char* lbase = (char*)&sF[w][0];
            const unsigned lstep = (unsigned)(rpi * RS4) * 4u;
            for (int it = 0; it < iters; ++it) {
                const float* gc = (g > gmax) ? gmax : g;   // pad rows reload
                __builtin_amdgcn_global_load_lds((as1_void*)gc,
                                                 (as3_void*)lbase, 16, 0, 0);
                g += gstep;
                lbase += lstep;
            }
        }
    } else {
        // rare tail/oversize fallback: scalar staging, always in-bounds
        int fh2 = FH;
        if (fh2 * RS4 > CAP) fh2 = CAP / RS4;
        for (int i = lane; i < fh2 * RS4; i += 64) {
            int fy = i / RS4;
            int fx = i - fy * RS4;
            int cx = fx < FW ? fx : (FW - 1);
            sF[w][i] = src[(size_t)fy * W + cx];
        }
    }

    __builtin_amdgcn_s_waitcnt(0);        // drain async LDS fills (+lgkm)
    __asm__ __volatile__("" ::: "memory");

    // ---- compute 49 bins from LDS (lanes 0..48) ----
    if (lane < NBIN) {
        int py = lane / POOL;
        int px = lane - POOL * py;
        int xa = 2 * px, xb = xa + 1;
        int xr0 = sXlo[w][xa] - rx0;
        int xr1 = sXlo[w][xb] - rx0;
        int xp0 = min(xr0 + 1, FW - 1);   // cap-x: weight 0, stay in-row
        int xp1 = min(xr1 + 1, FW - 1);
        float wxl0 = sWxl[w][xa], wxh0 = sWxh[w][xa];
        float wxl1 = sWxl[w][xb], wxh1 = sWxh[w][xb];
        const float* Fb = &sF[w][0];
        float acc = 0.0f;
        #pragma unroll
        for (int sy = 0; sy < 2; ++sy) {
            int ysi = 2 * py + sy;
            int yl = sYlo[w][ysi] - ry0;
            int yh = sYhi[w][ysi] - ry0;
            float wl = sWyl[w][ysi], wh = sWyh[w][ysi];
            const float* rl = Fb + yl * RS4;
            const float* rh = Fb + yh * RS4;
            float s0 = rl[xr0] * wxl0 + rl[xp0] * wxh0
                     + rl[xr1] * wxl1 + rl[xp1] * wxh1;
            float s1 = rh[xr0] * wxl0 + rh[xp0] * wxh0
                     + rh[xr1] * wxl1 + rh[xp1] * wxh1;
            acc += wl * s0 + wh * s1;
        }
        out[(size_t)unit * NBIN + lane] = acc * 0.25f;
    }
}

extern "C" void kernel_launch(void* const* d_in, const int* in_sizes, int n_in,
                              void* d_out, int out_size, void* d_ws, size_t ws_size,
                              hipStream_t stream) {
    const float* f0    = (const float*)d_in[0];
    const float* f1    = (const float*)d_in[1];
    const float* f2    = (const float*)d_in[2];
    const float* f3    = (const float*)d_in[3];
    const float* boxes = (const float*)d_in[4];
    const int*   bidx  = (const int*)d_in[5];
    float* out = (float*)d_out;

    int M = in_sizes[4] / 4;
    int units = M * NCH;
    int blocks = (units + WPB - 1) / WPB;
    hipLaunchKernelGGL(roi_align_kernel, dim3(blocks), dim3(256), 0, stream,
                       f0, f1, f2, f3, boxes, bidx, out, M);
}